// Round 11
// baseline (190.227 us; speedup 1.0000x reference)
//
#include <hip/hip_runtime.h>

// ---------------------------------------------------------------------------
// DigitConvolutionalModel: x(32768,784) -> conv3x3(valid) -> 676
//   -> relu(@W1(676,300)+b1) -> relu(@W2(300,300)+b2) -> @W3(300,10)+b3
//
// R17: PHASE ABLATION. Split fused_mlp into gemm1_k + tail_k sharing h1
// via workspace (bf16 A-frag order, 20MB). Motivation: 4 falsified
// whole-kernel theories (R8 barriers, R11 x-depth, R14 LDS-throughput,
// R16 convoy); MfmaUtil pinned 13-15% in all; never measured phases
// separately (guide Common-mistake #8; pre-committed in R12/R16).
//  - gemm1_k: R12 GEMM1 VERBATIM (verified best) + h1 transpose + coalesced
//    LDS->global dump. Expect ~38-46us, WRITE ~21MB (h1f, not spill).
//  - tail_k: GEMM2 A-frags from global h1f (contig 1KB, L2), B from W2f;
//    NO LDS/barriers until h2 handoff (40KB LDS, 2 barriers) + GEMM3.
//    Expect ~12-20us, MfmaUtil 25-40%.
//  - Decision rule R18: optimize whichever kernel dominates.
// ---------------------------------------------------------------------------

typedef __bf16 bf16_t;
typedef __bf16 bf16x8 __attribute__((ext_vector_type(8)));
typedef float  f32x4  __attribute__((ext_vector_type(4)));

#define MFMA16(a, b, c) __builtin_amdgcn_mfma_f32_16x16x32_bf16((a), (b), (c), 0, 0, 0)

#define W1F_ELEMS (25 * 20 * 64 * 8)  // 256000  (K=800, N=320)
#define W2F_ELEMS (10 * 20 * 64 * 8)  // 102400  (K=320, N=320)
#define W3F_ELEMS (10 * 1 * 64 * 8)   // 5120    (K=320, N=16)
#define H1F_GRPS  (512 * 2560)        // 512 blocks x 2560 bf16x8 (40KB each)

#define XSLOT 16384   // one x band: 64 rows x 256B (64 f32 cols)
#define XBASE 40960   // Bbuf = 2 * 1280 frags * 16B

// ---------------------------------------------------------------------------
__global__ void prep_weights(const float* __restrict__ conv_w,
                             const float* __restrict__ W1,
                             const float* __restrict__ W2,
                             const float* __restrict__ W3,
                             bf16_t* __restrict__ W1f,
                             bf16_t* __restrict__ W2f,
                             bf16_t* __restrict__ W3f) {
    int idx = blockIdx.x * 256 + threadIdx.x;
    if (idx < 800 * 320) {
        int k = idx / 320;
        int n = idx - k * 320;
        float v = 0.0f;
        if (k < 784 && n < 300) {
            int py = k / 28;
            int px = k - py * 28;
#pragma unroll
            for (int ky = 0; ky < 3; ++ky) {
                int oy = py - ky;
                if (oy < 0 || oy > 25) continue;
#pragma unroll
                for (int kx = 0; kx < 3; ++kx) {
                    int ox = px - kx;
                    if (ox < 0 || ox > 25) continue;
                    v += conv_w[ky * 3 + kx] * W1[(oy * 26 + ox) * 300 + n];
                }
            }
        }
        int kc = k >> 5, quad = (k >> 3) & 3, j = k & 7;
        int nt = n >> 4, nin = n & 15;
        W1f[(((kc * 20 + nt) * 64 + quad * 16 + nin) << 3) + j] = (bf16_t)v;
    } else if (idx < 800 * 320 + 320 * 320) {
        int i2 = idx - 800 * 320;
        int k = i2 / 320;
        int n = i2 - k * 320;
        float v = (k < 300 && n < 300) ? W2[k * 300 + n] : 0.0f;
        int kc = k >> 5, quad = (k >> 3) & 3, j = k & 7;
        int nt = n >> 4, nin = n & 15;
        W2f[(((kc * 20 + nt) * 64 + quad * 16 + nin) << 3) + j] = (bf16_t)v;
    } else if (idx < 800 * 320 + 320 * 320 + 320 * 16) {
        int i3 = idx - (800 * 320 + 320 * 320);
        int k = i3 / 16;
        int n = i3 - k * 16;
        float v = (k < 300 && n < 10) ? W3[k * 10 + n] : 0.0f;
        int kc = k >> 5, quad = (k >> 3) & 3, j = k & 7;
        W3f[(((kc * 64) + quad * 16 + n) << 3) + j] = (bf16_t)v;
    }
}

// async global -> LDS, 16B/lane; LDS base wave-uniform, global addr per-lane.
__device__ __forceinline__ void stage16(const void* g, void* l) {
    __builtin_amdgcn_global_load_lds(
        (const __attribute__((address_space(1))) void*)g,
        (__attribute__((address_space(3))) void*)l, 16, 0, 0);
}

#define VMW(N) asm volatile("s_waitcnt vmcnt(" #N ") lgkmcnt(0)" ::: "memory")
#define LGKM0() asm volatile("s_waitcnt lgkmcnt(0)" ::: "memory")
#define BARRIER()                         \
    __builtin_amdgcn_s_barrier();         \
    __builtin_amdgcn_sched_barrier(0)

// ---------------------------------------------------------------------------
// gemm1_k: h1 = relu(x @ W1eff + b1) in A-frag order -> h1f (global).
// R12's GEMM1 verbatim: 8 waves, wave w owns 4 m-tiles x (3|2) n-tiles,
// shared B dbuf staged via global_load_lds, x f32 band ring-2 (src-XOR
// swizzle), counted waits + per-chunk raw barriers.
// ---------------------------------------------------------------------------
__global__ __launch_bounds__(512, 4) void gemm1_k(
    const float* __restrict__ x, const float* __restrict__ b1,
    const bf16x8* __restrict__ W1f, bf16x8* __restrict__ h1f) {
    __shared__ __align__(16) unsigned char smem[XBASE + 2 * XSLOT];  // 72 KB
    bf16x8* Bb   = (bf16x8*)smem;  // [2][1280] B chunk dbuf
    bf16x8* hbuf = (bf16x8*)smem;  // 40 KB overlay after G1
    bf16_t* hb   = (bf16_t*)smem;

    const int tid = threadIdx.x;
    const int w   = tid >> 6;
    const int l   = tid & 63;
    const int q   = l >> 4;
    const int l15 = l & 15;
    const int r0  = blockIdx.x * 64;

    const bool t3    = (w < 4);
    const int  nt0   = t3 ? (w * 3) : (12 + (w - 4) * 2);
    const int  boff2 = t3 ? 128 : 64;

    f32x4 acc[4][3];
#pragma unroll
    for (int m = 0; m < 4; ++m)
#pragma unroll
        for (int j = 0; j < 3; ++j) acc[m][j] = (f32x4){0.f, 0.f, 0.f, 0.f};

#define STAGE_B(KC, BUF)                                                       \
    {                                                                          \
        const bf16x8* ws_ = W1f + (size_t)(KC)*1280 + l;                       \
        bf16x8* wd_ = Bb + (BUF)*1280;                                         \
        stage16(ws_ + w * 64, wd_ + w * 64);                                   \
        stage16(ws_ + (w + 8) * 64, wd_ + (w + 8) * 64);                       \
        if (w >= 4) stage16(ws_ + (w + 12) * 64, wd_ + (w + 12) * 64);         \
    }

#define STAGE_BAND(BAND)                                                       \
    {                                                                          \
        unsigned char* slot_ = smem + XBASE + ((BAND)&1) * XSLOT;              \
        if ((BAND) < 12) {                                                     \
            _Pragma("unroll")                                                  \
            for (int i_ = 0; i_ < 2; ++i_) {                                   \
                int row_ = w * 8 + i_ * 4 + (l >> 4);                          \
                int u_   = (l & 15) ^ (row_ & 7);                              \
                stage16(x + (size_t)(r0 + row_) * 784 + (BAND)*64 + u_ * 4,    \
                        slot_ + w * 2048 + i_ * 1024);                         \
            }                                                                  \
        } else {                                                               \
            int row_ = w * 8 + (l >> 3);                                       \
            int u_   = (l & 7) ^ (row_ & 7);                                   \
            const float* src_ = x + (size_t)(r0 + row_) * 784 +                \
                                ((u_ < 4) ? (768 + u_ * 4) : 0);               \
            stage16(src_, slot_ + w * 1024);                                   \
        }                                                                      \
    }

#define AFRAG(DST, SLOT, RS, KCL, MT)                                          \
    {                                                                          \
        int row_ = (MT)*16 + l15;                                              \
        int r7_  = row_ & 7;                                                   \
        float4 fa_ = *(const float4*)((SLOT) + row_ * (RS) +                   \
                     ((((KCL)*8 + q * 2 + 0) ^ r7_) << 4));                    \
        float4 fb_ = *(const float4*)((SLOT) + row_ * (RS) +                   \
                     ((((KCL)*8 + q * 2 + 1) ^ r7_) << 4));                    \
        bf16x8 t_;                                                             \
        t_[0] = (bf16_t)fa_.x; t_[1] = (bf16_t)fa_.y;                          \
        t_[2] = (bf16_t)fa_.z; t_[3] = (bf16_t)fa_.w;                          \
        t_[4] = (bf16_t)fb_.x; t_[5] = (bf16_t)fb_.y;                          \
        t_[6] = (bf16_t)fb_.z; t_[7] = (bf16_t)fb_.w;                          \
        DST = t_;                                                              \
    }

#define G1CHUNK(SLOT, RS, KCL, BUF)                                            \
    {                                                                          \
        bf16x8 a0, a1, a2, a3;                                                 \
        AFRAG(a0, SLOT, RS, KCL, 0) AFRAG(a1, SLOT, RS, KCL, 1)                \
        AFRAG(a2, SLOT, RS, KCL, 2) AFRAG(a3, SLOT, RS, KCL, 3)                \
        const bf16x8* bb_ = Bb + (BUF)*1280 + nt0 * 64 + l;                    \
        bf16x8 b0 = bb_[0], b1v = bb_[64], b2v = bb_[boff2];                   \
        acc[0][0] = MFMA16(a0, b0, acc[0][0]);                                 \
        acc[1][0] = MFMA16(a1, b0, acc[1][0]);                                 \
        acc[2][0] = MFMA16(a2, b0, acc[2][0]);                                 \
        acc[3][0] = MFMA16(a3, b0, acc[3][0]);                                 \
        acc[0][1] = MFMA16(a0, b1v, acc[0][1]);                                \
        acc[1][1] = MFMA16(a1, b1v, acc[1][1]);                                \
        acc[2][1] = MFMA16(a2, b1v, acc[2][1]);                                \
        acc[3][1] = MFMA16(a3, b1v, acc[3][1]);                                \
        if (t3) {                                                              \
            acc[0][2] = MFMA16(a0, b2v, acc[0][2]);                            \
            acc[1][2] = MFMA16(a1, b2v, acc[1][2]);                            \
            acc[2][2] = MFMA16(a2, b2v, acc[2][2]);                            \
            acc[3][2] = MFMA16(a3, b2v, acc[3][2]);                            \
        }                                                                      \
    }

    // prologue: B_0 + X_0; cold-start drain.
    STAGE_B(0, 0)
    STAGE_BAND(0)
    VMW(0);
    BARRIER();

    for (int b = 0; b <= 10; ++b) {
        unsigned char* xs = smem + XBASE + (b & 1) * XSLOT;
        const int k0 = 2 * b;
        STAGE_B(k0 + 1, (k0 + 1) & 1)
        STAGE_BAND(b + 1)
        G1CHUNK(xs, 256, 0, k0 & 1)
        VMW(2);
        BARRIER();
        STAGE_B(k0 + 2, (k0 + 2) & 1)
        G1CHUNK(xs, 256, 1, (k0 + 1) & 1)
        VMW(0);
        BARRIER();
    }
    {
        unsigned char* xs = smem + XBASE + XSLOT;  // slot 1
        STAGE_B(23, 1)
        STAGE_BAND(12)
        G1CHUNK(xs, 256, 0, 0)
        VMW(1);
        BARRIER();
        STAGE_B(24, 0)
        G1CHUNK(xs, 256, 1, 1)
        VMW(0);
        BARRIER();
    }
    {
        unsigned char* xs = smem + XBASE;
        G1CHUNK(xs, 128, 0, 0)
        LGKM0();
        BARRIER();  // all Bbuf/x reads done before hbuf overlay
    }

    // h1 = relu(C1+b1) -> hbuf (A-frag order), then coalesced dump to global
#define HSTORE(J, BIAS)                                                        \
    {                                                                          \
        int n = (nt0 + (J)) * 16 + l15;                                        \
        float bias = (n < 300) ? (BIAS)[n] : 0.0f;                             \
        int kh = n >> 5, quad = (n >> 3) & 3, jj = n & 7;                      \
        _Pragma("unroll")                                                      \
        for (int mt = 0; mt < 4; ++mt)                                         \
            _Pragma("unroll")                                                  \
            for (int r = 0; r < 4; ++r) {                                      \
                float v = acc[mt][(J)][r] + bias;                              \
                v = v > 0.f ? v : 0.f;                                         \
                hb[(((kh * 4 + mt) * 64 + quad * 16 + q * 4 + r) << 3) + jj] = \
                    (bf16_t)v;                                                 \
            }                                                                  \
    }

    HSTORE(0, b1)
    HSTORE(1, b1)
    if (t3) HSTORE(2, b1)
    LGKM0();
    BARRIER();  // h1 visible in LDS

    bf16x8* hg = h1f + (size_t)blockIdx.x * 2560;
#pragma unroll
    for (int i = 0; i < 5; ++i) {
        int t = i * 512 + tid;
        hg[t] = hbuf[t];  // ds_read_b128 + global_store_dwordx4, coalesced
    }
}

// ---------------------------------------------------------------------------
// tail_k: out = relu(h1 @ W2 + b2) @ W3 + b3. A-frags from global h1f
// (contiguous, L2); B from W2f/W3f (L2). No LDS/barriers until h2 handoff.
// ---------------------------------------------------------------------------
__global__ __launch_bounds__(512, 4) void tail_k(
    const bf16x8* __restrict__ h1f, const float* __restrict__ b2,
    const float* __restrict__ b3, const bf16x8* __restrict__ W2f,
    const bf16x8* __restrict__ W3f, float* __restrict__ out) {
    __shared__ __align__(16) bf16x8 hbuf[2560];  // 40 KB h2 staging
    bf16_t* hb = (bf16_t*)hbuf;

    const int tid = threadIdx.x;
    const int w   = tid >> 6;
    const int l   = tid & 63;
    const int q   = l >> 4;
    const int l15 = l & 15;
    const int r0  = blockIdx.x * 64;

    const bool t3    = (w < 4);
    const int  nt0   = t3 ? (w * 3) : (12 + (w - 4) * 2);
    const int  boff2 = t3 ? 128 : 64;

    f32x4 acc[4][3];
#pragma unroll
    for (int m = 0; m < 4; ++m)
#pragma unroll
        for (int j = 0; j < 3; ++j) acc[m][j] = (f32x4){0.f, 0.f, 0.f, 0.f};

    const bf16x8* hg  = h1f + (size_t)blockIdx.x * 2560;
    const bf16x8* bB2 = W2f + nt0 * 64 + l;

    // GEMM2: 10 chunks, everything from global; compiler pipelines loads.
#define G2CHUNKG(KC2)                                                          \
    {                                                                          \
        bf16x8 a0 = hg[((KC2)*4 + 0) * 64 + l];                                \
        bf16x8 a1 = hg[((KC2)*4 + 1) * 64 + l];                                \
        bf16x8 a2 = hg[((KC2)*4 + 2) * 64 + l];                                \
        bf16x8 a3 = hg[((KC2)*4 + 3) * 64 + l];                                \
        const bf16x8* bp = bB2 + (KC2)*1280;                                   \
        bf16x8 b0 = bp[0], b1v = bp[64], b2v = bp[boff2];                      \
        acc[0][0] = MFMA16(a0, b0, acc[0][0]);                                 \
        acc[1][0] = MFMA16(a1, b0, acc[1][0]);                                 \
        acc[2][0] = MFMA16(a2, b0, acc[2][0]);                                 \
        acc[3][0] = MFMA16(a3, b0, acc[3][0]);                                 \
        acc[0][1] = MFMA16(a0, b1v, acc[0][1]);                                \
        acc[1][1] = MFMA16(a1, b1v, acc[1][1]);                                \
        acc[2][1] = MFMA16(a2, b1v, acc[2][1]);                                \
        acc[3][1] = MFMA16(a3, b1v, acc[3][1]);                                \
        if (t3) {                                                              \
            acc[0][2] = MFMA16(a0, b2v, acc[0][2]);                            \
            acc[1][2] = MFMA16(a1, b2v, acc[1][2]);                            \
            acc[2][2] = MFMA16(a2, b2v, acc[2][2]);                            \
            acc[3][2] = MFMA16(a3, b2v, acc[3][2]);                            \
        }                                                                      \
    }

    G2CHUNKG(0) G2CHUNKG(1) G2CHUNKG(2) G2CHUNKG(3) G2CHUNKG(4)
    G2CHUNKG(5) G2CHUNKG(6) G2CHUNKG(7) G2CHUNKG(8) G2CHUNKG(9)

    // h2 = relu(C2+b2) -> hbuf (first LDS use; no barrier needed before)
    HSTORE(0, b2)
    HSTORE(1, b2)
    if (t3) HSTORE(2, b2)
    LGKM0();
    BARRIER();  // h2 visible

    // GEMM3: waves 0-3 (mt=w); W3f frags from global
    if (w < 4) {
        f32x4 acc3 = (f32x4){0.f, 0.f, 0.f, 0.f};
#pragma unroll
        for (int kc3 = 0; kc3 < 10; ++kc3)
            acc3 = MFMA16(hbuf[(kc3 * 4 + w) * 64 + l], W3f[kc3 * 64 + l], acc3);
        if (l15 < 10) {
            float bias = b3[l15];
#pragma unroll
            for (int r = 0; r < 4; ++r)
                out[(size_t)(r0 + w * 16 + q * 4 + r) * 10 + l15] = acc3[r] + bias;
        }
    }
}

// ---------------------------------------------------------------------------
extern "C" void kernel_launch(void* const* d_in, const int* in_sizes, int n_in,
                              void* d_out, int out_size, void* d_ws, size_t ws_size,
                              hipStream_t stream) {
    const float* x      = (const float*)d_in[0];
    const float* conv_w = (const float*)d_in[1];
    const float* W1     = (const float*)d_in[2];
    const float* b1     = (const float*)d_in[3];
    const float* W2     = (const float*)d_in[4];
    const float* b2     = (const float*)d_in[5];
    const float* W3     = (const float*)d_in[6];
    const float* b3     = (const float*)d_in[7];
    float* out = (float*)d_out;

    char* ws = (char*)d_ws;
    bf16_t* W1f = (bf16_t*)(ws);
    bf16_t* W2f = (bf16_t*)(ws + (size_t)W1F_ELEMS * 2);
    bf16_t* W3f = (bf16_t*)(ws + (size_t)(W1F_ELEMS + W2F_ELEMS) * 2);
    bf16x8* h1f = (bf16x8*)(ws + (((size_t)(W1F_ELEMS + W2F_ELEMS + W3F_ELEMS) * 2 + 255) & ~(size_t)255));
    size_t need = (((size_t)(W1F_ELEMS + W2F_ELEMS + W3F_ELEMS) * 2 + 255) & ~(size_t)255) +
                  (size_t)H1F_GRPS * 16;
    if (ws_size < need) return;

    int prep_total = 800 * 320 + 320 * 320 + 320 * 16;  // 363520
    prep_weights<<<(prep_total + 255) / 256, 256, 0, stream>>>(
        conv_w, W1, W2, W3, W1f, W2f, W3f);

    gemm1_k<<<512, 512, 0, stream>>>(x, b1, (const bf16x8*)W1f, h1f);
    tail_k<<<512, 512, 0, stream>>>((const bf16x8*)h1f, b2, b3,
                                    (const bf16x8*)W2f, (const bf16x8*)W3f, out);
}